// Round 1
// baseline (570.261 us; speedup 1.0000x reference)
//
#include <hip/hip_runtime.h>
#include <math.h>

typedef __bf16 bf16;
typedef __bf16 bf16x8 __attribute__((ext_vector_type(8)));
typedef __bf16 bf16x4 __attribute__((ext_vector_type(4)));
typedef float f32x4 __attribute__((ext_vector_type(4)));

constexpr int BATCH = 2;
constexpr int SEQ   = 2048;
constexpr int HID   = 2048;
constexpr int NHEAD = 16;
constexpr int NKV   = 8;
constexpr int HD    = 128;
constexpr int MROWS = BATCH * SEQ; // 4096

#define DEVINL __device__ __forceinline__

DEVINL void async16(void* l, const void* g) {
  __builtin_amdgcn_global_load_lds((const __attribute__((address_space(1))) void*)g,
                                   (__attribute__((address_space(3))) void*)l, 16, 0, 0);
}

DEVINL f32x4 mfma16(bf16x8 a, bf16x8 b, f32x4 c) {
  return __builtin_amdgcn_mfma_f32_16x16x32_bf16(a, b, c, 0, 0, 0);
}

DEVINL f32x4 fzero4() { f32x4 z; z[0] = 0.f; z[1] = 0.f; z[2] = 0.f; z[3] = 0.f; return z; }

// ---------------- elementwise cast f32 -> bf16 ----------------
__global__ __launch_bounds__(256) void cast_f32_bf16(const float* __restrict__ x,
                                                     bf16* __restrict__ y, int n) {
  int i = (blockIdx.x * 256 + threadIdx.x) * 4;
  if (i + 3 < n) {
    float4 v = *(const float4*)(x + i);
    bf16x4 o;
    o[0] = (bf16)v.x; o[1] = (bf16)v.y; o[2] = (bf16)v.z; o[3] = (bf16)v.w;
    *(bf16x4*)(y + i) = o;
  }
}

// ---------------- W transpose f32[K][N] -> bf16 WT[N][K] ----------------
__global__ __launch_bounds__(256) void wtrans(const float* __restrict__ W,
                                              bf16* __restrict__ WT, int K, int N) {
  __shared__ bf16 t[64][65];
  int n0 = blockIdx.x * 64, k0 = blockIdx.y * 64;
  for (int i = threadIdx.x; i < 4096; i += 256) {
    int r = i >> 6, c = i & 63;
    t[r][c] = (bf16)W[(size_t)(k0 + r) * N + n0 + c];
  }
  __syncthreads();
  for (int i = threadIdx.x; i < 4096; i += 256) {
    int r = i >> 6, c = i & 63;
    WT[(size_t)(n0 + r) * K + k0 + c] = t[c][r];
  }
}

// ---------------- V[b*S+s][kvh*128+d] -> VT[(b*8+kvh)*128+d][s] ----------------
__global__ __launch_bounds__(256) void vtrans(const bf16* __restrict__ V, bf16* __restrict__ VT) {
  __shared__ bf16 t[64][65];
  int s0 = blockIdx.x * 64, d0 = blockIdx.y * 64;
  int bh = blockIdx.z, b = bh >> 3, kvh = bh & 7;
  for (int i = threadIdx.x; i < 4096; i += 256) {
    int r = i >> 6, c = i & 63;
    t[r][c] = V[(size_t)(b * SEQ + s0 + r) * (NKV * HD) + kvh * HD + d0 + c];
  }
  __syncthreads();
  for (int i = threadIdx.x; i < 4096; i += 256) {
    int r = i >> 6, c = i & 63;
    VT[((size_t)bh * HD + d0 + r) * SEQ + s0 + c] = t[c][r];
  }
}

// ---------------- RoPE tables: cos/sin [SEQ][64] ----------------
__global__ void rope_tab(float* __restrict__ ct, float* __restrict__ st) {
  int s = blockIdx.x, d = threadIdx.x;
  float freq = powf(10000.0f, -(float)d * (1.0f / 64.0f));
  float a = (float)s * freq;
  ct[s * 64 + d] = cosf(a);
  st[s * 64 + d] = sinf(a);
}

// ---------------- GEMM: C = A[M,K] @ BT[N,K]^T ----------------
// EPI: 0 = bf16 store, 1 = RoPE + bf16 store, 2 = f32 store
// 128x128 tile, BK=64, 4 waves each 32 rows x 128 cols.
// LDS linear (global_load_lds), reads XOR-swizzled; source pre-inverse-swizzled.
template <int EPI>
__global__ __launch_bounds__(256) void gemm_bf16k(const bf16* __restrict__ A,
                                                  const bf16* __restrict__ BT,
                                                  void* __restrict__ Cout, int M, int N, int K,
                                                  const float* __restrict__ ct,
                                                  const float* __restrict__ st) {
  __shared__ alignas(16) char ldsA[16384];
  __shared__ alignas(16) char ldsB[16384];
  const int tid = threadIdx.x;
  const int lane = tid & 63;
  const int w = tid >> 6;
  const int l15 = lane & 15;
  const int l4 = lane >> 4;
  const int row0 = blockIdx.y * 128;
  const int col0 = blockIdx.x * 128;

  f32x4 acc[2][8];
#pragma unroll
  for (int mt = 0; mt < 2; mt++)
#pragma unroll
    for (int nt = 0; nt < 8; nt++) acc[mt][nt] = fzero4();

  const int ciB = w * 64 + lane;
  const int nk = K >> 6;
  for (int kt = 0; kt < nk; ++kt) {
    const int k0 = kt << 6;
    __syncthreads();
#pragma unroll
    for (int j = 0; j < 4; j++) {
      int ci = j * 256 + ciB;
      int r = ci >> 3, ps = ci & 7, ls = ps ^ (r & 7);
      char* dstA = ldsA + (j * 256 + w * 64) * 16;
      char* dstB = ldsB + (j * 256 + w * 64) * 16;
      async16(dstA, A + (size_t)(row0 + r) * K + k0 + ls * 8);
      async16(dstB, BT + (size_t)(col0 + r) * K + k0 + ls * 8);
    }
    asm volatile("s_waitcnt vmcnt(0)" ::: "memory");
    __syncthreads();

    bf16x8 af[2][2];
#pragma unroll
    for (int mt = 0; mt < 2; mt++)
#pragma unroll
      for (int kc = 0; kc < 2; kc++) {
        int r = w * 32 + mt * 16 + l15;
        int off = ((r << 7) + ((kc * 4 + l4) << 4)) ^ ((r & 7) << 4);
        af[mt][kc] = *(const bf16x8*)(ldsA + off);
      }
#pragma unroll
    for (int nt = 0; nt < 8; nt++) {
#pragma unroll
      for (int kc = 0; kc < 2; kc++) {
        int r = nt * 16 + l15;
        int off = ((r << 7) + ((kc * 4 + l4) << 4)) ^ ((r & 7) << 4);
        bf16x8 bfr = *(const bf16x8*)(ldsB + off);
        acc[0][nt] = mfma16(af[0][kc], bfr, acc[0][nt]);
        acc[1][nt] = mfma16(af[1][kc], bfr, acc[1][nt]);
      }
    }
  }

#pragma unroll
  for (int mt = 0; mt < 2; mt++)
#pragma unroll
    for (int nt = 0; nt < 8; nt++)
#pragma unroll
      for (int rg = 0; rg < 4; rg++) {
        int row = row0 + w * 32 + mt * 16 + l4 * 4 + rg;
        int col = col0 + nt * 16 + l15;
        float v = acc[mt][nt][rg];
        if (EPI == 2) {
          ((float*)Cout)[(size_t)row * N + col] = v;
        } else if (EPI == 0) {
          ((bf16*)Cout)[(size_t)row * N + col] = (bf16)v;
        } else {
          int d = col & 127;          // col0 is a multiple of 128 -> head-aligned
          int s = row & (SEQ - 1);    // rows = b*SEQ + s
          int ntp = (nt < 4) ? nt + 4 : nt - 4;  // pair d +/- 64 lives in same lane
          float pv = (nt < 4) ? -acc[mt][ntp][rg] : acc[mt][ntp][rg];
          float cc = ct[s * 64 + (d & 63)];
          float ss = st[s * 64 + (d & 63)];
          ((bf16*)Cout)[(size_t)row * N + col] = (bf16)(v * cc + pv * ss);
        }
      }
}

// ---------------- Flash attention ----------------
// grid (qtile=16, head=16, batch=2), 256 thr / 4 waves; wave = 32 q-rows.
// K tile [64 kv][128 d], VT tile [128 d][64 kv] in swizzled LDS; P via per-wave LDS.
__global__ __launch_bounds__(256) void attn(const bf16* __restrict__ Q,
                                            const bf16* __restrict__ Kg,
                                            const bf16* __restrict__ VT,
                                            bf16* __restrict__ O) {
  __shared__ alignas(16) char ldsK[16384];
  __shared__ alignas(16) char ldsV[16384];
  __shared__ alignas(16) char ldsP[16384];
  const int tid = threadIdx.x, lane = tid & 63, w = tid >> 6;
  const int l15 = lane & 15, l4 = lane >> 4;
  const int qt = blockIdx.x, h = blockIdx.y, b = blockIdx.z;
  const int kvh = h >> 1;  // GQA groups=2 (repeat_interleave)
  const int rowQ0 = b * SEQ + qt * 128 + w * 32;

  bf16x8 qf[2][4];
#pragma unroll
  for (int mt = 0; mt < 2; mt++)
#pragma unroll
    for (int kc = 0; kc < 4; kc++)
      qf[mt][kc] = *(const bf16x8*)(Q + (size_t)(rowQ0 + mt * 16 + l15) * (NHEAD * HD) +
                                    h * HD + kc * 32 + l4 * 8);

  f32x4 o[2][8];
#pragma unroll
  for (int mt = 0; mt < 2; mt++)
#pragma unroll
    for (int dt = 0; dt < 8; dt++) o[mt][dt] = fzero4();
  float mst[2][4], lst[2][4];
#pragma unroll
  for (int mt = 0; mt < 2; mt++)
#pragma unroll
    for (int rg = 0; rg < 4; rg++) { mst[mt][rg] = -3.0e38f; lst[mt][rg] = 0.0f; }

  const int ciB = w * 64 + lane;
  char* myP = ldsP + w * 4096;  // per-wave P[32][64] bf16
  const float rs = 0.08838834764831845f;  // 1/sqrt(128)

  for (int t = 0; t < SEQ / 64; ++t) {
    const int kv0 = t * 64;
    __syncthreads();
#pragma unroll
    for (int j = 0; j < 4; j++) {
      int ci = j * 256 + ciB;
      {  // K tile: 64 rows x 16 slots of 16B; swizzle low 3 slot bits
        int r = ci >> 4, ps = ci & 15;
        int ls = (ps & 8) | ((ps ^ (r & 7)) & 7);
        async16(ldsK + (j * 256 + w * 64) * 16,
                Kg + (size_t)(b * SEQ + kv0 + r) * (NKV * HD) + kvh * HD + ls * 8);
      }
      {  // VT tile: 128 rows x 8 slots
        int r = ci >> 3, ps = ci & 7, ls = ps ^ (r & 7);
        async16(ldsV + (j * 256 + w * 64) * 16,
                VT + ((size_t)(b * NKV + kvh) * HD + r) * SEQ + kv0 + ls * 8);
      }
    }
    asm volatile("s_waitcnt vmcnt(0)" ::: "memory");
    __syncthreads();

    // scores: S[32 q][64 kv]
    f32x4 sc[2][4];
#pragma unroll
    for (int mt = 0; mt < 2; mt++)
#pragma unroll
      for (int nt = 0; nt < 4; nt++) sc[mt][nt] = fzero4();
#pragma unroll
    for (int kc = 0; kc < 4; kc++) {
#pragma unroll
      for (int nt = 0; nt < 4; nt++) {
        int r = nt * 16 + l15;
        int off = ((r << 8) + ((kc * 4 + l4) << 4)) ^ ((r & 7) << 4);
        bf16x8 kf = *(const bf16x8*)(ldsK + off);
        sc[0][nt] = mfma16(qf[0][kc], kf, sc[0][nt]);
        sc[1][nt] = mfma16(qf[1][kc], kf, sc[1][nt]);
      }
    }

    // softcap + online softmax (row reduce via shfl_xor within 16-lane group)
#pragma unroll
    for (int mt = 0; mt < 2; mt++)
#pragma unroll
      for (int rg = 0; rg < 4; rg++) {
        float vmax = -1.0e30f;
#pragma unroll
        for (int nt = 0; nt < 4; nt++) {
          float y = sc[mt][nt][rg] * rs * 0.02f;  // score / (sqrt(128)*50)
          float e = __expf(-2.0f * fabsf(y));     // stable: arg <= 0
          float cv = 50.0f * copysignf((1.0f - e) / (1.0f + e), y);
          sc[mt][nt][rg] = cv;
          vmax = fmaxf(vmax, cv);
        }
        vmax = fmaxf(vmax, __shfl_xor(vmax, 1));
        vmax = fmaxf(vmax, __shfl_xor(vmax, 2));
        vmax = fmaxf(vmax, __shfl_xor(vmax, 4));
        vmax = fmaxf(vmax, __shfl_xor(vmax, 8));
        float mo = mst[mt][rg];
        float mn = fmaxf(mo, vmax);
        float sf = __expf(mo - mn);
        float rsum = 0.0f;
#pragma unroll
        for (int nt = 0; nt < 4; nt++) {
          float p = __expf(sc[mt][nt][rg] - mn);
          sc[mt][nt][rg] = p;
          rsum += p;
        }
        rsum += __shfl_xor(rsum, 1);
        rsum += __shfl_xor(rsum, 2);
        rsum += __shfl_xor(rsum, 4);
        rsum += __shfl_xor(rsum, 8);
        mst[mt][rg] = mn;
        lst[mt][rg] = lst[mt][rg] * sf + rsum;
#pragma unroll
        for (int dt = 0; dt < 8; dt++) o[mt][dt][rg] *= sf;
        // P -> per-wave LDS (swizzled), C-layout -> A-layout reshuffle
        int pr = mt * 16 + l4 * 4 + rg;
#pragma unroll
        for (int nt = 0; nt < 4; nt++) {
          int off = ((pr << 7) + ((nt * 16 + l15) << 1)) ^ ((pr & 7) << 4);
          *(bf16*)(myP + off) = (bf16)sc[mt][nt][rg];
        }
      }

    // PV: O += P[32 q][64 kv] @ V[64 kv][128 d]
    bf16x8 pa[2][2];
#pragma unroll
    for (int mt = 0; mt < 2; mt++)
#pragma unroll
      for (int kc = 0; kc < 2; kc++) {
        int r = mt * 16 + l15;
        int off = ((r << 7) + ((kc * 4 + l4) << 4)) ^ ((r & 7) << 4);
        pa[mt][kc] = *(const bf16x8*)(myP + off);
      }
#pragma unroll
    for (int dt = 0; dt < 8; dt++) {
#pragma unroll
      for (int kc = 0; kc < 2; kc++) {
        int r = dt * 16 + l15;
        int off = ((r << 7) + ((kc * 4 + l4) << 4)) ^ ((r & 7) << 4);
        bf16x8 vb = *(const bf16x8*)(ldsV + off);
        o[0][dt] = mfma16(pa[0][kc], vb, o[0][dt]);
        o[1][dt] = mfma16(pa[1][kc], vb, o[1][dt]);
      }
    }
  }

#pragma unroll
  for (int mt = 0; mt < 2; mt++)
#pragma unroll
    for (int rg = 0; rg < 4; rg++) {
      float inv = 1.0f / lst[mt][rg];
      int row = rowQ0 + mt * 16 + l4 * 4 + rg;
#pragma unroll
      for (int dt = 0; dt < 8; dt++) {
        int col = h * HD + dt * 16 + l15;
        O[(size_t)row * (NHEAD * HD) + col] = (bf16)(o[mt][dt][rg] * inv);
      }
    }
}

extern "C" void kernel_launch(void* const* d_in, const int* in_sizes, int n_in,
                              void* d_out, int out_size, void* d_ws, size_t ws_size,
                              hipStream_t stream) {
  const float* X  = (const float*)d_in[0];
  const float* Wq = (const float*)d_in[1];
  const float* Wk = (const float*)d_in[2];
  const float* Wv = (const float*)d_in[3];
  const float* Wo = (const float*)d_in[4];
  float* out = (float*)d_out;

  char* ws = (char*)d_ws;
  size_t off = 0;
  auto alloc = [&](size_t bytes) {
    void* p = ws + off;
    off += (bytes + 255) & ~(size_t)255;
    return p;
  };
  bf16* Xb  = (bf16*)alloc((size_t)MROWS * HID * 2);
  bf16* WqT = (bf16*)alloc((size_t)2048 * 2048 * 2);
  bf16* WkT = (bf16*)alloc((size_t)1024 * 2048 * 2);
  bf16* WvT = (bf16*)alloc((size_t)1024 * 2048 * 2);
  bf16* WoT = (bf16*)alloc((size_t)2048 * 2048 * 2);
  bf16* Qb  = (bf16*)alloc((size_t)MROWS * 2048 * 2);
  bf16* Kb  = (bf16*)alloc((size_t)MROWS * 1024 * 2);
  bf16* Vb  = (bf16*)alloc((size_t)MROWS * 1024 * 2);
  bf16* VTb = (bf16*)alloc((size_t)16 * 128 * 2048 * 2);
  bf16* AOb = (bf16*)alloc((size_t)MROWS * 2048 * 2);
  float* ct = (float*)alloc((size_t)SEQ * 64 * 4);
  float* st = (float*)alloc((size_t)SEQ * 64 * 4);

  cast_f32_bf16<<<(MROWS * HID) / 1024, 256, 0, stream>>>(X, Xb, MROWS * HID);
  wtrans<<<dim3(32, 32), 256, 0, stream>>>(Wq, WqT, 2048, 2048);
  wtrans<<<dim3(16, 32), 256, 0, stream>>>(Wk, WkT, 2048, 1024);
  wtrans<<<dim3(16, 32), 256, 0, stream>>>(Wv, WvT, 2048, 1024);
  wtrans<<<dim3(32, 32), 256, 0, stream>>>(Wo, WoT, 2048, 2048);
  rope_tab<<<SEQ, 64, 0, stream>>>(ct, st);
  gemm_bf16k<1><<<dim3(16, 32), 256, 0, stream>>>(Xb, WqT, Qb, MROWS, 2048, 2048, ct, st);
  gemm_bf16k<1><<<dim3(8, 32), 256, 0, stream>>>(Xb, WkT, Kb, MROWS, 1024, 2048, ct, st);
  gemm_bf16k<0><<<dim3(8, 32), 256, 0, stream>>>(Xb, WvT, Vb, MROWS, 1024, 2048, nullptr, nullptr);
  vtrans<<<dim3(32, 2, 16), 256, 0, stream>>>(Vb, VTb);
  attn<<<dim3(16, 16, 2), 256, 0, stream>>>(Qb, Kb, VTb, AOb);
  gemm_bf16k<2><<<dim3(16, 32), 256, 0, stream>>>(AOb, WoT, out, MROWS, 2048, 2048, nullptr, nullptr);

  (void)in_sizes; (void)n_in; (void)out_size; (void)ws_size;
}